// Round 9
// baseline (128.097 us; speedup 1.0000x reference)
//
#include <hip/hip_runtime.h>
#include <cmath>

#define KCLS 10
#define NCELL 3721          // 61*61
#define BIGV  0x0FFFFFFF

// d_out layout (all float32), concatenated in reference return order
#define OUT_PROB 0
#define OUT_LAB  37210
#define OUT_BOX  74420
#define OUT_VALID 223300

// ---------------------------------------------------------------------------
// DPP wave64 sum on the VALU pipe (v_add_f32_dpp); result lands in lane 63.
#define DPPADD(x, ctrl) \
    x += __int_as_float(__builtin_amdgcn_update_dpp( \
        0, __float_as_int(x), ctrl, 0xf, 0xf, true))

__device__ __forceinline__ float wave_sum64(float x) {
    DPPADD(x, 0x111);   // row_shr:1
    DPPADD(x, 0x112);   // row_shr:2
    DPPADD(x, 0x114);   // row_shr:4
    DPPADD(x, 0x118);   // row_shr:8
    DPPADD(x, 0x142);   // row_bcast:15
    DPPADD(x, 0x143);   // row_bcast:31
    return x;           // lane 63 holds the 64-lane sum
}

// ---------------- Stage 0: transpose W -> WT[k][d] -------------------------
// Makes the weight operand lane-coalesced for k1a (lane = d). 480 KB once.
__global__ __launch_bounds__(256) void k0_transpose(
    const float* __restrict__ W, float* __restrict__ WT)
{
    const int d = blockIdx.x * 256 + threadIdx.x;   // 48 blocks -> 0..12287
    const float2 a0 = *(const float2*)(W + (size_t)d * KCLS + 0);
    const float2 a1 = *(const float2*)(W + (size_t)d * KCLS + 2);
    const float2 a2 = *(const float2*)(W + (size_t)d * KCLS + 4);
    const float2 a3 = *(const float2*)(W + (size_t)d * KCLS + 6);
    const float2 a4 = *(const float2*)(W + (size_t)d * KCLS + 8);
    WT[0 * 12288 + d] = a0.x;  WT[1 * 12288 + d] = a0.y;
    WT[2 * 12288 + d] = a1.x;  WT[3 * 12288 + d] = a1.y;
    WT[4 * 12288 + d] = a2.x;  WT[5 * 12288 + d] = a2.y;
    WT[6 * 12288 + d] = a3.x;  WT[7 * 12288 + d] = a3.y;
    WT[8 * 12288 + d] = a4.x;  WT[9 * 12288 + d] = a4.y;
}

// ---------------- Stage 1a: partial logits (K-split x4) --------------------
// Grid 1952 = 61 r x 8 cg x 4 q; 256 threads = 4 waves; lane = d.
// Thread owns d-pairs d0 = 3072q + 2*tid + 512u, u=0..5 (q-quarter of K).
// Both operand streams lane-coalesced (512B/wave/instr):
//   wt[k] = WT[k*12288 + d0]                      (10 float2)
//   xv[p] = x[(16r+i)*3072 + 48*(c0+p) + t]       (8 float2; 2 | 192 so a
//           d-pair never straddles a pixel row)
// 8x10 register outer product: 160 FMA / 18 loads per iter.
// amdgpu_waves_per_eu(3,3): occupancy pinned at 3 waves/EU -> allocator has
// no incentive to shrink below ~170 VGPRs -> acc[8][10]+wt+xv (~135) stays
// in arch VGPRs, no AGPR shuffling (r8's VGPR=64 sandbag, 2x VALU ops).
__global__ __launch_bounds__(256)
__attribute__((amdgpu_waves_per_eu(3, 3))) void k1a_partial(
    const float* __restrict__ x, const float* __restrict__ WT,
    float* __restrict__ partial)
{
    const int tid = threadIdx.x;
    const int bid = blockIdx.x;            // 0..1951
    const int q   = bid & 3;               // K-quarter
    const int cg  = (bid >> 2) & 7;        // col group
    const int r   = bid >> 5;              // 0..60
    const int c0  = (cg == 7) ? 53 : cg * 8;   // overlap cols: bit-identical
                                               // recompute (same d order)
    __shared__ float red[4][8][KCLS];      // [wave][patch][k] 1.25 KiB

    float acc[8][KCLS];
#pragma unroll
    for (int p = 0; p < 8; ++p)
#pragma unroll
        for (int k = 0; k < KCLS; ++k) acc[p][k] = 0.0f;

    // d0 = 3072q + 2tid = 192*i0 + t0  (i = row-in-patch, t = 3*j+ch)
    const int dq = 3072 * q + 2 * tid;
    int i = dq / 192;
    int t = dq - i * 192;
    const float* wtb = WT + dq;            // + 12288*k + 512*u

    for (int u = 0; u < 6; ++u) {
        const float* xb = x + (size_t)(r * 16 + i) * 3072 + 48 * c0 + t;
        const float* wb = wtb + (u << 9);

        float2 wt[KCLS];
#pragma unroll
        for (int k = 0; k < KCLS; ++k) wt[k] = *(const float2*)(wb + 12288 * k);

        float2 xv[4];
#pragma unroll
        for (int p = 0; p < 4; ++p) xv[p] = *(const float2*)(xb + 48 * p);
#pragma unroll
        for (int p = 0; p < 4; ++p)
#pragma unroll
            for (int k = 0; k < KCLS; ++k)
                acc[p][k] += xv[p].x * wt[k].x + xv[p].y * wt[k].y;

#pragma unroll
        for (int p = 0; p < 4; ++p) xv[p] = *(const float2*)(xb + 192 + 48 * p);
#pragma unroll
        for (int p = 0; p < 4; ++p)
#pragma unroll
            for (int k = 0; k < KCLS; ++k)
                acc[4 + p][k] += xv[p].x * wt[k].x + xv[p].y * wt[k].y;

        // d0 += 512 = 2*192 + 128
        t += 128; i += 2;
        if (t >= 192) { t -= 192; ++i; }
    }

    // wave reduction (VALU pipe), partials to LDS
    const int w = tid >> 6;
#pragma unroll
    for (int p = 0; p < 8; ++p)
#pragma unroll
        for (int k = 0; k < KCLS; ++k) {
            const float s = wave_sum64(acc[p][k]);
            if ((tid & 63) == 63) red[w][p][k] = s;
        }
    __syncthreads();

    // 80 threads: cross-wave sum -> partial[q][r][c][k]
    if (tid < 80) {
        const int p = tid / 10, k = tid - p * 10;
        const float s = red[0][p][k] + red[1][p][k] + red[2][p][k] + red[3][p][k];
        partial[(size_t)q * 37210 + (size_t)r * 610 + (size_t)(c0 + p) * 10 + k] = s;
    }
}

// ---------------- Stage 1b: reduce 4 partials + bias + softmax -------------
__global__ __launch_bounds__(640) void k1b_softmax(
    const float* __restrict__ partial, const float* __restrict__ b,
    float* __restrict__ out)
{
    const int r   = blockIdx.x;           // 0..60
    const int tid = threadIdx.x;
    __shared__ double lgs[61][KCLS];

    if (tid < 610) {
        const int c = tid / 10, k = tid - c * 10;
        const float* p = partial + (size_t)r * 610 + tid;
        double s = (double)b[k];
#pragma unroll
        for (int q = 0; q < 4; ++q) s += (double)p[(size_t)q * 37210];
        lgs[c][k] = s;
    }
    __syncthreads();

    if (tid < 61) {
        double l[KCLS];
#pragma unroll
        for (int k = 0; k < KCLS; ++k) l[k] = lgs[tid][k];
        double m = l[0];
#pragma unroll
        for (int k = 1; k < KCLS; ++k) m = fmax(m, l[k]);
        double e[KCLS], ssum = 0.0;
#pragma unroll
        for (int k = 0; k < KCLS; ++k) { e[k] = exp(l[k] - m); ssum += e[k]; }
        const double inv = 1.0 / ssum;
        float* po = out + OUT_PROB + (size_t)(r * 61 + tid) * KCLS;
#pragma unroll
        for (int k = 0; k < KCLS; ++k) po[k] = (float)(e[k] * inv);
    }
}

// ---------------- Stage 2+3 fused: CC (union-find hooking) + boxes ---------
// One block per class. Labels stored as LDS OFFSETS (off = (r+1)*64 + c+1):
// min-off == min-idx (both lexicographic in (r,c)). Root chase + atomicMin
// hooking = path compression -> ~3-6 rounds instead of O(diameter).
__global__ __launch_bounds__(1024) void k2_cc_boxes(float* __restrict__ out)
{
    const int k   = blockIdx.x;
    const int tid = threadIdx.x;

    __shared__ int lab[63 * 64];
    __shared__ int act[NCELL];
    __shared__ int nact, changed;
    __shared__ int rmn[NCELL + 1], rmx[NCELL + 1], cmn[NCELL + 1], cmx[NCELL + 1];

    for (int idx = tid; idx < 63 * 64; idx += 1024) lab[idx] = BIGV;
    for (int s = tid; s <= NCELL; s += 1024) {
        rmn[s] = 0x7fffffff; cmn[s] = 0x7fffffff; rmx[s] = -1; cmx[s] = -1;
    }
    if (tid == 0) nact = 0;
    __syncthreads();

    for (int idx = tid; idx < NCELL; idx += 1024) {
        const float pv = out[OUT_PROB + (size_t)idx * KCLS + k];
        if (pv > 0.7f) {
            const int r = idx / 61, c = idx - r * 61;
            const int off = (r + 1) * 64 + (c + 1);
            lab[off] = off;
            act[atomicAdd(&nact, 1)] = off;
        }
    }
    __syncthreads();
    const int na = nact;

    for (int round = 0; round < 128; ++round) {
        if (tid == 0) changed = 0;
        __syncthreads();
        bool ch = false;
        for (int ii = tid; ii < na; ii += 1024) {
            const int off = act[ii];
            const int v = lab[off];
            int m = v, t;
            t = lab[off - 1];  if (t < m) m = t;
            t = lab[off + 1];  if (t < m) m = t;
            t = lab[off - 64]; if (t < m) m = t;
            t = lab[off + 64]; if (t < m) m = t;
            if (m < v) {
                int p = lab[m];                       // chase to current root
                while (p < m) { m = p; p = lab[m]; }  // strictly decreasing
                atomicMin(&lab[off], m);              // compress self
                atomicMin(&lab[v],   m);              // hook old root (union)
                ch = true;
            }
        }
        if (ch) changed = 1;       // benign race
        __syncthreads();
        if (changed == 0) break;   // no writes between the barriers -> uniform
        __syncthreads();           // protect next round's reset
    }

    // write labels (convert off -> idx+1)
    for (int idx = tid; idx < NCELL; idx += 1024) {
        const int r = idx / 61, c = idx - r * 61;
        const int v = lab[(r + 1) * 64 + (c + 1)];
        const int lv = (v < BIGV) ? ((v >> 6) * 61 - 61 + (v & 63)) : 0;
        out[OUT_LAB + (size_t)idx * KCLS + k] = (float)lv;
    }

    // boxes: segment min/max over active cells only
    for (int ii = tid; ii < na; ii += 1024) {
        const int off = act[ii];
        const int v = lab[off];
        const int lb = (v >> 6) * 61 - 61 + (v & 63);
        const int r = (off >> 6) - 1, c = (off & 63) - 1;
        atomicMin(&rmn[lb], r); atomicMax(&rmx[lb], r);
        atomicMin(&cmn[lb], c); atomicMax(&cmx[lb], c);
    }
    __syncthreads();

    for (int s = tid; s <= NCELL; s += 1024) {
        const bool val = (s > 0) && (rmx[s] >= 0);
        float* bo = out + OUT_BOX + (size_t)(k * (NCELL + 1) + s) * 4;
        if (val) {
            bo[0] = (float)(rmn[s] - 1);
            bo[1] = (float)(cmn[s] - 1);
            bo[2] = (float)(rmx[s] + 1);
            bo[3] = (float)(cmx[s] + 1);
        } else {
            bo[0] = 0.0f; bo[1] = 0.0f; bo[2] = 0.0f; bo[3] = 0.0f;
        }
        out[OUT_VALID + (size_t)k * (NCELL + 1) + s] = val ? 1.0f : 0.0f;
    }
}

extern "C" void kernel_launch(void* const* d_in, const int* in_sizes, int n_in,
                              void* d_out, int out_size, void* d_ws, size_t ws_size,
                              hipStream_t stream) {
    const float* x = (const float*)d_in[0];   // (1,1024,1024,3) f32
    const float* W = (const float*)d_in[1];   // (12288,10) f32
    const float* b = (const float*)d_in[2];   // (10,) f32
    float* out     = (float*)d_out;
    float* WT      = (float*)d_ws;                     // 10*12288 f32 = 480 KB
    float* partial = (float*)d_ws + 10 * 12288;        // 4*61*61*10 = 595 KB

    k0_transpose<<<dim3(48),   dim3(256),  0, stream>>>(W, WT);
    k1a_partial <<<dim3(1952), dim3(256),  0, stream>>>(x, WT, partial);
    k1b_softmax <<<dim3(61),   dim3(640),  0, stream>>>(partial, b, out);
    k2_cc_boxes <<<dim3(KCLS), dim3(1024), 0, stream>>>(out);
}